// Round 6
// baseline (180.085 us; speedup 1.0000x reference)
//
#include <hip/hip_runtime.h>
#include <cstdint>
#include <cstddef>

typedef unsigned short u16;
typedef __attribute__((ext_vector_type(4))) float f32x4;
typedef __attribute__((ext_vector_type(8))) short bf16x8;

#define LN_EPS 1e-5f

__device__ __forceinline__ u16 f2bf(float f) {
  unsigned int u = __float_as_uint(f);
  u += 0x7FFFu + ((u >> 16) & 1u);
  return (u16)(u >> 16);
}

__device__ __forceinline__ float l0gate(float loga) {
  float s = 1.0f / (1.0f + expf(-loga));
  float v = s * 1.2f - 0.1f;   // sigmoid*(zeta-gamma)+gamma, zeta=1.1 gamma=-0.1
  return fminf(fmaxf(v, 0.0f), 1.0f);
}

__device__ __forceinline__ void llds16(u16* lds, const u16* g) {
  __builtin_amdgcn_global_load_lds(
      (const __attribute__((address_space(1))) unsigned int*)g,
      (__attribute__((address_space(3))) unsigned int*)lds, 16, 0, 0);
}

// ---- prep: fold L0 gate into bf16 weights ----
__global__ __launch_bounds__(256) void prep_weights(
    const float* __restrict__ dw, const float* __restrict__ uw,
    const float* __restrict__ dloga, const float* __restrict__ uloga,
    const int* __restrict__ lang,
    u16* __restrict__ dwb, u16* __restrict__ uwb) {
  const int lid = lang[0];
  const unsigned i = blockIdx.x * 256u + threadIdx.x;
  dwb[i] = f2bf(dw[i] * l0gate(dloga[lid * 2048 + (i & 2047u)]));
  uwb[i] = f2bf(uw[i] * l0gate(uloga[lid * 512 + (i & 511u)]));
}

// ---- LayerNorm over D=2048 + bf16 cast; one block per token row ----
__global__ __launch_bounds__(256) void ln_kernel(
    const float* __restrict__ x, const float* __restrict__ g,
    const float* __restrict__ b, u16* __restrict__ h1) {
  const int row = blockIdx.x;
  const int tid = threadIdx.x;
  const float4* xr = (const float4*)(x + (size_t)row * 2048);
  float4 v0 = xr[tid * 2 + 0];
  float4 v1 = xr[tid * 2 + 1];
  float s = v0.x + v0.y + v0.z + v0.w + v1.x + v1.y + v1.z + v1.w;
  float q = v0.x * v0.x + v0.y * v0.y + v0.z * v0.z + v0.w * v0.w +
            v1.x * v1.x + v1.y * v1.y + v1.z * v1.z + v1.w * v1.w;
#pragma unroll
  for (int off = 32; off > 0; off >>= 1) {
    s += __shfl_down(s, off, 64);
    q += __shfl_down(q, off, 64);
  }
  __shared__ float ss[4], sq[4], sstat[2];
  const int wave = tid >> 6, lane = tid & 63;
  if (lane == 0) { ss[wave] = s; sq[wave] = q; }
  __syncthreads();
  if (tid == 0) {
    float S = ss[0] + ss[1] + ss[2] + ss[3];
    float Q = sq[0] + sq[1] + sq[2] + sq[3];
    float mu = S * (1.0f / 2048.0f);
    float var = Q * (1.0f / 2048.0f) - mu * mu;
    sstat[0] = mu;
    sstat[1] = rsqrtf(var + LN_EPS);
  }
  __syncthreads();
  const float mu = sstat[0], rs = sstat[1];
  const float4* g4 = (const float4*)g;
  const float4* b4 = (const float4*)b;
  float4 ga = g4[tid * 2], gb = g4[tid * 2 + 1];
  float4 ba = b4[tid * 2], bb = b4[tid * 2 + 1];
  union { u16 us[8]; uint4 u; } p;
  p.us[0] = f2bf((v0.x - mu) * rs * ga.x + ba.x);
  p.us[1] = f2bf((v0.y - mu) * rs * ga.y + ba.y);
  p.us[2] = f2bf((v0.z - mu) * rs * ga.z + ba.z);
  p.us[3] = f2bf((v0.w - mu) * rs * ga.w + ba.w);
  p.us[4] = f2bf((v1.x - mu) * rs * gb.x + bb.x);
  p.us[5] = f2bf((v1.y - mu) * rs * gb.y + bb.y);
  p.us[6] = f2bf((v1.z - mu) * rs * gb.z + bb.z);
  p.us[7] = f2bf((v1.w - mu) * rs * gb.w + bb.w);
  ((uint4*)(h1 + (size_t)row * 2048))[tid] = p.u;
}

// ---- 128x64 tile, BK=32, dbuf counted-vmcnt bf16 GEMM + T1 XCD swizzle ----
// C[M,N] = A[M,K] * B[N,K]^T, both K-contiguous. LDS: 32 KB -> 4+ blocks/CU.
// Waves 2Mx2N, wave tile 64x32, acc[4][2]. LDS-transposed coalesced epilogue.
// EPI=1: +bias, relu, bf16 store.  EPI=2: +bias +resid, f32 store.
template <int EPI>
__global__ __launch_bounds__(256, 4) void gemm_bt(
    const u16* __restrict__ A, const u16* __restrict__ B,
    int M, int N, int K, int NX,
    const float* __restrict__ bias,
    const float* __restrict__ resid,
    void* __restrict__ outp) {
  __shared__ __align__(16) char smem[32768];
  u16* As = (u16*)smem;                 // [buf][128][32] bf16: 2 x 8 KB
  u16* Bs = (u16*)(smem + 16384);       // [buf][64][32]  bf16: 2 x 4 KB
  float* Cs = (float*)smem;             // epilogue alias: [128][64] f32 = 32 KB

  const int tid = threadIdx.x;
  const int wave = tid >> 6, lane = tid & 63;
  const int wr = (wave >> 1) * 64;    // wave row offset
  const int wcc = (wave & 1) * 32;    // wave col offset
  const int lrow = lane & 15, lk = lane >> 4;

  // T1: XCD-aware bijective swizzle (nwg % 8 == 0)
  const int nwg = gridDim.x;
  const int wg = (blockIdx.x & 7) * (nwg >> 3) + (blockIdx.x >> 3);
  const int bx = wg % NX, by = wg / NX;
  const size_t m0 = (size_t)by * 128;
  const size_t n0 = (size_t)bx * 64;

  f32x4 acc[4][2] = {};

  // staging: 1 KB chunks, wave-uniform LDS base, lane l -> row q*16+(l>>2),
  // k-slot (l&3)*8. A: 8 chunks (2/wave), B: 4 chunks (1/wave). 3 loads/thread.
  const int crow = lane >> 2;
  const int ckk = (lane & 3) * 8;
  auto STAGE = [&](int buf, int k0) {
#pragma unroll
    for (int c = 0; c < 2; ++c) {
      const int q = wave * 2 + c;                 // 0..7 -> rows q*16..q*16+15
      llds16(As + buf * 4096 + q * 512,
             A + (m0 + q * 16 + crow) * (size_t)K + (k0 + ckk));
    }
    llds16(Bs + buf * 2048 + wave * 512,
           B + (n0 + wave * 16 + crow) * (size_t)K + (k0 + ckk));
  };

  const int NT = K >> 5;
  STAGE(0, 0);                                    // 3 vmem in flight

  for (int t = 0; t < NT; ++t) {
    const int cur = t & 1;
    if (t + 1 < NT) {
      STAGE(cur ^ 1, (t + 1) << 5);               // 6 in flight
      asm volatile("s_waitcnt vmcnt(3)" ::: "memory");  // tile t landed
    } else {
      asm volatile("s_waitcnt vmcnt(0)" ::: "memory");
    }
    __builtin_amdgcn_s_barrier();
    asm volatile("" ::: "memory");

    const u16* Ab = As + cur * 4096;
    const u16* Bb = Bs + cur * 2048;
    bf16x8 af[4], bfr[2];
#pragma unroll
    for (int m = 0; m < 4; ++m)
      af[m] = *(const bf16x8*)&Ab[(wr + m * 16 + lrow) * 32 + lk * 8];
#pragma unroll
    for (int n = 0; n < 2; ++n)
      bfr[n] = *(const bf16x8*)&Bb[(wcc + n * 16 + lrow) * 32 + lk * 8];
    __builtin_amdgcn_s_setprio(1);
#pragma unroll
    for (int m = 0; m < 4; ++m)
#pragma unroll
      for (int n = 0; n < 2; ++n)
        acc[m][n] = __builtin_amdgcn_mfma_f32_16x16x32_bf16(af[m], bfr[n],
                                                            acc[m][n], 0, 0, 0);
    __builtin_amdgcn_s_setprio(0);

    asm volatile("s_waitcnt lgkmcnt(0)" ::: "memory");
    __builtin_amdgcn_s_barrier();
    asm volatile("" ::: "memory");
  }

  // ---- epilogue: acc -> Cs[128][64] (rotated: col' = (c+8*(row>>2)) & 63,
  // 2-way banks = free) -> coalesced readback. T14: resid prefetch in flight
  // under the LDS transpose (raw barrier, no vmcnt drain).
  float4 rsd[8];
  if (EPI == 2) {
#pragma unroll
    for (int j = 0; j < 8; ++j) {
      const int flat = tid * 4 + j * 1024;
      const int row = flat >> 6, c = flat & 63;
      rsd[j] = *(const float4*)&resid[(m0 + row) * (size_t)N + n0 + c];
    }
  }

#pragma unroll
  for (int n = 0; n < 2; ++n) {
    const int c = wcc + n * 16 + lrow;
    const float bv = bias[n0 + c];
#pragma unroll
    for (int m = 0; m < 4; ++m) {
#pragma unroll
      for (int r = 0; r < 4; ++r) {
        const int row = wr + m * 16 + lk * 4 + r;
        Cs[row * 64 + ((c + ((row >> 2) << 3)) & 63)] = acc[m][n][r] + bv;
      }
    }
  }
  asm volatile("s_waitcnt lgkmcnt(0)" ::: "memory");
  __builtin_amdgcn_s_barrier();
  asm volatile("" ::: "memory");

  if (EPI == 2) {
#pragma unroll
    for (int j = 0; j < 8; ++j) {
      const int flat = tid * 4 + j * 1024;
      const int row = flat >> 6, c = flat & 63;
      const float4 cc = *(const float4*)&Cs[row * 64 + ((c + ((row >> 2) << 3)) & 63)];
      float4 o;
      o.x = cc.x + rsd[j].x; o.y = cc.y + rsd[j].y;
      o.z = cc.z + rsd[j].z; o.w = cc.w + rsd[j].w;
      *(float4*)&((float*)outp)[(m0 + row) * (size_t)N + n0 + c] = o;
    }
  } else {
    // 256 threads x 8 elems x 4 iters = 8192 = full 128x64 tile
#pragma unroll
    for (int j = 0; j < 4; ++j) {
      const int flat = tid * 8 + j * 2048;
      const int row = flat >> 6, c = flat & 63;
      const int cp = (c + ((row >> 2) << 3)) & 63;   // 8-chunk never wraps
      const float4 c0 = *(const float4*)&Cs[row * 64 + cp];
      const float4 c1 = *(const float4*)&Cs[row * 64 + cp + 4];
      union { u16 us[8]; uint4 u; } p;
      p.us[0] = f2bf(fmaxf(c0.x, 0.0f)); p.us[1] = f2bf(fmaxf(c0.y, 0.0f));
      p.us[2] = f2bf(fmaxf(c0.z, 0.0f)); p.us[3] = f2bf(fmaxf(c0.w, 0.0f));
      p.us[4] = f2bf(fmaxf(c1.x, 0.0f)); p.us[5] = f2bf(fmaxf(c1.y, 0.0f));
      p.us[6] = f2bf(fmaxf(c1.z, 0.0f)); p.us[7] = f2bf(fmaxf(c1.w, 0.0f));
      *(uint4*)&((u16*)outp)[(m0 + row) * (size_t)N + n0 + c] = p.u;
    }
  }
}

extern "C" void kernel_launch(void* const* d_in, const int* in_sizes, int n_in,
                              void* d_out, int out_size, void* d_ws, size_t ws_size,
                              hipStream_t stream) {
  const float* x         = (const float*)d_in[0];
  const float* down_w    = (const float*)d_in[1];
  const float* down_b    = (const float*)d_in[2];
  const float* up_w      = (const float*)d_in[3];
  const float* up_b      = (const float*)d_in[4];
  const float* ln_g      = (const float*)d_in[5];
  const float* ln_b      = (const float*)d_in[6];
  const float* down_loga = (const float*)d_in[7];
  const float* up_loga   = (const float*)d_in[8];
  const int*   lang      = (const int*)d_in[9];

  const int D = 2048, BNK = 512;
  const int M = in_sizes[0] / D;  // 16384

  char* ws = (char*)d_ws;
  u16* h1  = (u16*)ws;                                   // [M][D] bf16
  u16* h2  = (u16*)(ws + (size_t)M * D * 2);             // [M][BNK] bf16
  u16* dwb = (u16*)(ws + (size_t)M * D * 2 + (size_t)M * BNK * 2);  // [BNK][D]
  u16* uwb = dwb + (size_t)BNK * D;                      // [D][BNK]

  prep_weights<<<(BNK * D) / 256, 256, 0, stream>>>(down_w, up_w, down_loga,
                                                    up_loga, lang, dwb, uwb);
  ln_kernel<<<M, 256, 0, stream>>>(x, ln_g, ln_b, h1);
  const int nwg1 = (BNK / 64) * (M / 128);   // 1024
  const int nwg2 = (D / 64) * (M / 128);     // 4096
  gemm_bt<1><<<nwg1, 256, 0, stream>>>(h1, dwb, M, BNK, D, BNK / 64,
                                       down_b, nullptr, h2);
  gemm_bt<2><<<nwg2, 256, 0, stream>>>(h2, uwb, M, D, BNK, D / 64,
                                       up_b, x, d_out);
}

// Round 7
// 177.137 us; speedup vs baseline: 1.0166x; 1.0166x over previous
//
#include <hip/hip_runtime.h>
#include <cstdint>
#include <cstddef>

typedef unsigned short u16;
typedef __attribute__((ext_vector_type(4))) float f32x4;
typedef __attribute__((ext_vector_type(8))) short bf16x8;

#define LN_EPS 1e-5f

__device__ __forceinline__ u16 f2bf(float f) {
  unsigned int u = __float_as_uint(f);
  u += 0x7FFFu + ((u >> 16) & 1u);
  return (u16)(u >> 16);
}

__device__ __forceinline__ float l0gate(float loga) {
  float s = 1.0f / (1.0f + expf(-loga));
  float v = s * 1.2f - 0.1f;   // sigmoid*(zeta-gamma)+gamma, zeta=1.1 gamma=-0.1
  return fminf(fmaxf(v, 0.0f), 1.0f);
}

__device__ __forceinline__ void llds16(u16* lds, const u16* g) {
  __builtin_amdgcn_global_load_lds(
      (const __attribute__((address_space(1))) unsigned int*)g,
      (__attribute__((address_space(3))) unsigned int*)lds, 16, 0, 0);
}

// ---- prep: fold L0 gate into bf16 weights ----
__global__ __launch_bounds__(256) void prep_weights(
    const float* __restrict__ dw, const float* __restrict__ uw,
    const float* __restrict__ dloga, const float* __restrict__ uloga,
    const int* __restrict__ lang,
    u16* __restrict__ dwb, u16* __restrict__ uwb) {
  const int lid = lang[0];
  const unsigned i = blockIdx.x * 256u + threadIdx.x;
  dwb[i] = f2bf(dw[i] * l0gate(dloga[lid * 2048 + (i & 2047u)]));
  uwb[i] = f2bf(uw[i] * l0gate(uloga[lid * 512 + (i & 511u)]));
}

// ---- LayerNorm over D=2048 + bf16 cast; one block per token row ----
__global__ __launch_bounds__(256) void ln_kernel(
    const float* __restrict__ x, const float* __restrict__ g,
    const float* __restrict__ b, u16* __restrict__ h1) {
  const int row = blockIdx.x;
  const int tid = threadIdx.x;
  const float4* xr = (const float4*)(x + (size_t)row * 2048);
  float4 v0 = xr[tid * 2 + 0];
  float4 v1 = xr[tid * 2 + 1];
  float s = v0.x + v0.y + v0.z + v0.w + v1.x + v1.y + v1.z + v1.w;
  float q = v0.x * v0.x + v0.y * v0.y + v0.z * v0.z + v0.w * v0.w +
            v1.x * v1.x + v1.y * v1.y + v1.z * v1.z + v1.w * v1.w;
#pragma unroll
  for (int off = 32; off > 0; off >>= 1) {
    s += __shfl_down(s, off, 64);
    q += __shfl_down(q, off, 64);
  }
  __shared__ float ss[4], sq[4], sstat[2];
  const int wave = tid >> 6, lane = tid & 63;
  if (lane == 0) { ss[wave] = s; sq[wave] = q; }
  __syncthreads();
  if (tid == 0) {
    float S = ss[0] + ss[1] + ss[2] + ss[3];
    float Q = sq[0] + sq[1] + sq[2] + sq[3];
    float mu = S * (1.0f / 2048.0f);
    float var = Q * (1.0f / 2048.0f) - mu * mu;
    sstat[0] = mu;
    sstat[1] = rsqrtf(var + LN_EPS);
  }
  __syncthreads();
  const float mu = sstat[0], rs = sstat[1];
  const float4* g4 = (const float4*)g;
  const float4* b4 = (const float4*)b;
  float4 ga = g4[tid * 2], gb = g4[tid * 2 + 1];
  float4 ba = b4[tid * 2], bb = b4[tid * 2 + 1];
  union { u16 us[8]; uint4 u; } p;
  p.us[0] = f2bf((v0.x - mu) * rs * ga.x + ba.x);
  p.us[1] = f2bf((v0.y - mu) * rs * ga.y + ba.y);
  p.us[2] = f2bf((v0.z - mu) * rs * ga.z + ba.z);
  p.us[3] = f2bf((v0.w - mu) * rs * ga.w + ba.w);
  p.us[4] = f2bf((v1.x - mu) * rs * gb.x + bb.x);
  p.us[5] = f2bf((v1.y - mu) * rs * gb.y + bb.y);
  p.us[6] = f2bf((v1.z - mu) * rs * gb.z + bb.z);
  p.us[7] = f2bf((v1.w - mu) * rs * gb.w + bb.w);
  ((uint4*)(h1 + (size_t)row * 2048))[tid] = p.u;
}

// ---- 128x64 tile, BK=32, dbuf counted-vmcnt bf16 GEMM ----
// Swizzle (both sides, rule #21): LDS[r][p] = global slot p ^ ((r>>1)&3)
// -> ds_read_b128 bank pattern 2-way (free). T1 XCD swizzle on grid.
// C[M,N] = A[M,K] * B[N,K]^T. Waves 2Mx2N, wave tile 64x32, acc[4][2].
// EPI=1: +bias, relu, bf16 store.  EPI=2: +bias +resid, f32 store.
template <int EPI>
__global__ __launch_bounds__(256, 4) void gemm_bt(
    const u16* __restrict__ A, const u16* __restrict__ B,
    int M, int N, int K, int NX,
    const float* __restrict__ bias,
    const float* __restrict__ resid,
    void* __restrict__ outp) {
  __shared__ __align__(16) char smem[32768];
  u16* As = (u16*)smem;                 // [buf][128][32] bf16: 2 x 8 KB
  u16* Bs = (u16*)(smem + 16384);       // [buf][64][32]  bf16: 2 x 4 KB
  float* Cs = (float*)smem;             // epilogue alias: [128][64] f32 = 32 KB

  const int tid = threadIdx.x;
  const int wave = tid >> 6, lane = tid & 63;
  const int wr = (wave >> 1) * 64;    // wave row offset
  const int wcc = (wave & 1) * 32;    // wave col offset
  const int lrow = lane & 15, lk = lane >> 4;

  // T1: XCD-aware bijective swizzle (nwg % 8 == 0)
  const int nwg = gridDim.x;
  const int wg = (blockIdx.x & 7) * (nwg >> 3) + (blockIdx.x >> 3);
  const int bx = wg % NX, by = wg / NX;
  const size_t m0 = (size_t)by * 128;
  const size_t n0 = (size_t)bx * 64;

  f32x4 acc[4][2] = {};

  // staging: 1 KB chunks, lane l -> LDS row l>>2, 16B-slot l&3 (linear dest);
  // pre-swizzled global k-slot = (l&3) ^ ((l>>3)&3). 4-lane groups still read
  // one contiguous 64 B row chunk -> coalesced.
  const int crow = lane >> 2;
  const int ckk = ((lane & 3) ^ ((lane >> 3) & 3)) * 8;
  auto STAGE = [&](int buf, int k0) {
#pragma unroll
    for (int c = 0; c < 2; ++c) {
      const int q = wave * 2 + c;                 // 0..7 -> rows q*16..q*16+15
      llds16(As + buf * 4096 + q * 512,
             A + (m0 + q * 16 + crow) * (size_t)K + (k0 + ckk));
    }
    llds16(Bs + buf * 2048 + wave * 512,
           B + (n0 + wave * 16 + crow) * (size_t)K + (k0 + ckk));
  };

  // read position for global k-slot lk at row r: lk ^ ((r>>1)&3); since
  // wr+m*16 is a multiple of 16, (r>>1)&3 == (lrow>>1)&3 (wave-uniform per lane)
  const int pos8 = ((unsigned)(lk ^ ((lrow >> 1) & 3))) * 8;

  const int NT = K >> 5;
  STAGE(0, 0);                                    // 3 vmem in flight

  for (int t = 0; t < NT; ++t) {
    const int cur = t & 1;
    if (t + 1 < NT) {
      STAGE(cur ^ 1, (t + 1) << 5);               // 6 in flight
      asm volatile("s_waitcnt vmcnt(3)" ::: "memory");  // tile t landed
    } else {
      asm volatile("s_waitcnt vmcnt(0)" ::: "memory");
    }
    __builtin_amdgcn_s_barrier();
    asm volatile("" ::: "memory");

    const u16* Ab = As + cur * 4096;
    const u16* Bb = Bs + cur * 2048;
    bf16x8 af[4], bfr[2];
#pragma unroll
    for (int m = 0; m < 4; ++m)
      af[m] = *(const bf16x8*)&Ab[(wr + m * 16 + lrow) * 32 + pos8];
#pragma unroll
    for (int n = 0; n < 2; ++n)
      bfr[n] = *(const bf16x8*)&Bb[(wcc + n * 16 + lrow) * 32 + pos8];
    __builtin_amdgcn_s_setprio(1);
#pragma unroll
    for (int m = 0; m < 4; ++m)
#pragma unroll
      for (int n = 0; n < 2; ++n)
        acc[m][n] = __builtin_amdgcn_mfma_f32_16x16x32_bf16(af[m], bfr[n],
                                                            acc[m][n], 0, 0, 0);
    __builtin_amdgcn_s_setprio(0);

    asm volatile("s_waitcnt lgkmcnt(0)" ::: "memory");
    __builtin_amdgcn_s_barrier();
    asm volatile("" ::: "memory");
  }

  // ---- epilogue: acc -> Cs[128][64] (rotated: col' = (c+8*(row>>2)) & 63,
  // 2-way banks = free) -> coalesced readback. T14: resid prefetch batched
  // (4+4 float4) to cap VGPR; raw barrier keeps batch A in flight.
  float4 rsdA[4], rsdB[4];
  if (EPI == 2) {
#pragma unroll
    for (int j = 0; j < 4; ++j) {
      const int flat = tid * 4 + j * 1024;
      const int row = flat >> 6, c = flat & 63;
      rsdA[j] = *(const float4*)&resid[(m0 + row) * (size_t)N + n0 + c];
    }
  }

#pragma unroll
  for (int n = 0; n < 2; ++n) {
    const int c = wcc + n * 16 + lrow;
    const float bv = bias[n0 + c];
#pragma unroll
    for (int m = 0; m < 4; ++m) {
#pragma unroll
      for (int r = 0; r < 4; ++r) {
        const int row = wr + m * 16 + lk * 4 + r;
        Cs[row * 64 + ((c + ((row >> 2) << 3)) & 63)] = acc[m][n][r] + bv;
      }
    }
  }
  asm volatile("s_waitcnt lgkmcnt(0)" ::: "memory");
  __builtin_amdgcn_s_barrier();
  asm volatile("" ::: "memory");

  if (EPI == 2) {
#pragma unroll
    for (int j = 0; j < 4; ++j) {            // batch B issued under batch A's use
      const int flat = tid * 4 + (j + 4) * 1024;
      const int row = flat >> 6, c = flat & 63;
      rsdB[j] = *(const float4*)&resid[(m0 + row) * (size_t)N + n0 + c];
    }
#pragma unroll
    for (int j = 0; j < 8; ++j) {
      const int flat = tid * 4 + j * 1024;
      const int row = flat >> 6, c = flat & 63;
      const float4 cc = *(const float4*)&Cs[row * 64 + ((c + ((row >> 2) << 3)) & 63)];
      const float4 rv = (j < 4) ? rsdA[j] : rsdB[j - 4];
      float4 o;
      o.x = cc.x + rv.x; o.y = cc.y + rv.y;
      o.z = cc.z + rv.z; o.w = cc.w + rv.w;
      *(float4*)&((float*)outp)[(m0 + row) * (size_t)N + n0 + c] = o;
    }
  } else {
    // 256 threads x 8 elems x 4 iters = 8192 = full 128x64 tile
#pragma unroll
    for (int j = 0; j < 4; ++j) {
      const int flat = tid * 8 + j * 2048;
      const int row = flat >> 6, c = flat & 63;
      const int cp = (c + ((row >> 2) << 3)) & 63;   // 8-chunk never wraps
      const float4 c0 = *(const float4*)&Cs[row * 64 + cp];
      const float4 c1 = *(const float4*)&Cs[row * 64 + cp + 4];
      union { u16 us[8]; uint4 u; } p;
      p.us[0] = f2bf(fmaxf(c0.x, 0.0f)); p.us[1] = f2bf(fmaxf(c0.y, 0.0f));
      p.us[2] = f2bf(fmaxf(c0.z, 0.0f)); p.us[3] = f2bf(fmaxf(c0.w, 0.0f));
      p.us[4] = f2bf(fmaxf(c1.x, 0.0f)); p.us[5] = f2bf(fmaxf(c1.y, 0.0f));
      p.us[6] = f2bf(fmaxf(c1.z, 0.0f)); p.us[7] = f2bf(fmaxf(c1.w, 0.0f));
      *(uint4*)&((u16*)outp)[(m0 + row) * (size_t)N + n0 + c] = p.u;
    }
  }
}

extern "C" void kernel_launch(void* const* d_in, const int* in_sizes, int n_in,
                              void* d_out, int out_size, void* d_ws, size_t ws_size,
                              hipStream_t stream) {
  const float* x         = (const float*)d_in[0];
  const float* down_w    = (const float*)d_in[1];
  const float* down_b    = (const float*)d_in[2];
  const float* up_w      = (const float*)d_in[3];
  const float* up_b      = (const float*)d_in[4];
  const float* ln_g      = (const float*)d_in[5];
  const float* ln_b      = (const float*)d_in[6];
  const float* down_loga = (const float*)d_in[7];
  const float* up_loga   = (const float*)d_in[8];
  const int*   lang      = (const int*)d_in[9];

  const int D = 2048, BNK = 512;
  const int M = in_sizes[0] / D;  // 16384

  char* ws = (char*)d_ws;
  u16* h1  = (u16*)ws;                                   // [M][D] bf16
  u16* h2  = (u16*)(ws + (size_t)M * D * 2);             // [M][BNK] bf16
  u16* dwb = (u16*)(ws + (size_t)M * D * 2 + (size_t)M * BNK * 2);  // [BNK][D]
  u16* uwb = dwb + (size_t)BNK * D;                      // [D][BNK]

  prep_weights<<<(BNK * D) / 256, 256, 0, stream>>>(down_w, up_w, down_loga,
                                                    up_loga, lang, dwb, uwb);
  ln_kernel<<<M, 256, 0, stream>>>(x, ln_g, ln_b, h1);
  const int nwg1 = (BNK / 64) * (M / 128);   // 1024
  const int nwg2 = (D / 64) * (M / 128);     // 4096
  gemm_bt<1><<<nwg1, 256, 0, stream>>>(h1, dwb, M, BNK, D, BNK / 64,
                                       down_b, nullptr, h2);
  gemm_bt<2><<<nwg2, 256, 0, stream>>>(h2, uwb, M, D, BNK, D / 64,
                                       up_b, x, d_out);
}

// Round 8
// 160.664 us; speedup vs baseline: 1.1209x; 1.1025x over previous
//
#include <hip/hip_runtime.h>
#include <cstdint>
#include <cstddef>

typedef unsigned short u16;
typedef __attribute__((ext_vector_type(4))) float f32x4;
typedef __attribute__((ext_vector_type(8))) short bf16x8;

#define LN_EPS 1e-5f

__device__ __forceinline__ u16 f2bf(float f) {
  unsigned int u = __float_as_uint(f);
  u += 0x7FFFu + ((u >> 16) & 1u);
  return (u16)(u >> 16);
}

__device__ __forceinline__ float l0gate(float loga) {
  float s = 1.0f / (1.0f + expf(-loga));
  float v = s * 1.2f - 0.1f;   // sigmoid*(zeta-gamma)+gamma
  return fminf(fmaxf(v, 0.0f), 1.0f);
}

__device__ __forceinline__ void llds16(u16* lds, const u16* g) {
  __builtin_amdgcn_global_load_lds(
      (const __attribute__((address_space(1))) unsigned int*)g,
      (__attribute__((address_space(3))) unsigned int*)lds, 16, 0, 0);
}

// ---- prep: fold L0 gate (and ln gamma for down path) into bf16 weights ----
__global__ __launch_bounds__(256) void prep_weights(
    const float* __restrict__ dw, const float* __restrict__ uw,
    const float* __restrict__ dloga, const float* __restrict__ uloga,
    const int* __restrict__ lang, const float* __restrict__ g,
    u16* __restrict__ dwb, u16* __restrict__ uwb) {
  const int lid = lang[0];
  const unsigned i = blockIdx.x * 256u + threadIdx.x;
  // dwb2[n][d] = down_w * gate_d * ln_gamma_d   (LN fused algebraically)
  dwb[i] = f2bf(dw[i] * l0gate(dloga[lid * 2048 + (i & 2047u)]) * g[i & 2047u]);
  uwb[i] = f2bf(uw[i] * l0gate(uloga[lid * 512 + (i & 511u)]));
}

// ---- prep_uv: u[n] = sum_d W*gate*g ; wv[n] = sum_d W*gate*ln_b + down_b ----
__global__ __launch_bounds__(256) void prep_uv(
    const float* __restrict__ dw, const float* __restrict__ dloga,
    const int* __restrict__ lang, const float* __restrict__ g,
    const float* __restrict__ lnb, const float* __restrict__ down_b,
    float* __restrict__ u, float* __restrict__ wv) {
  const int lid = lang[0];
  const int n = blockIdx.x * 4 + (threadIdx.x >> 6);
  const int lane = threadIdx.x & 63;
  float su = 0.0f, sv = 0.0f;
  for (int d = lane; d < 2048; d += 64) {
    const float w = dw[n * 2048 + d] * l0gate(dloga[lid * 2048 + d]);
    su += w * g[d];
    sv += w * lnb[d];
  }
#pragma unroll
  for (int off = 32; off > 0; off >>= 1) {
    su += __shfl_down(su, off, 64);
    sv += __shfl_down(sv, off, 64);
  }
  if (lane == 0) { u[n] = su; wv[n] = sv + down_b[n]; }
}

// ---- gemm1 with fused LN: h2 = relu( rs*(x*Wg^T - mu*u) + wv ) ----
// x [M][2048] f32, Wg [512][2048] bf16 (gate,gamma folded). 128x128 tile, BK=64.
// A reg-staged (f32 load -> stats accum -> bf16 -> linear ds_write, read-side
// slot swizzle via source permutation); B via global_load_lds (R5 pattern).
__global__ __launch_bounds__(256) void gemm1_ln(
    const float* __restrict__ X, const u16* __restrict__ Bw,
    int M, const float* __restrict__ uu, const float* __restrict__ wvv,
    u16* __restrict__ h2out) {
  const int K = 2048;
  __shared__ __align__(16) char smem[65536];
  u16* As = (u16*)smem;                 // [2][128][64] bf16
  u16* Bs = (u16*)(smem + 32768);       // [2][128][64] bf16
  float* Cs = (float*)smem;             // epilogue alias [128][128] f32
  __shared__ float stats[128][2];       // mu, rs per tile row

  const int tid = threadIdx.x;
  const int wave = tid >> 6, lane = tid & 63;
  const int wr = (wave >> 1) * 64, wc = (wave & 1) * 64;
  const int lrow = lane & 15, lk = lane >> 4;

  const int nwg = gridDim.x;            // 512, %8==0
  const int wg = (blockIdx.x & 7) * (nwg >> 3) + (blockIdx.x >> 3);
  const int bx = wg & 3, by = wg >> 2;  // NX=4
  const size_t m0 = (size_t)by * 128, n0 = (size_t)bx * 128;

  f32x4 acc[4][4] = {};
  float sx[4] = {0.f, 0.f, 0.f, 0.f}, qx[4] = {0.f, 0.f, 0.f, 0.f};

  // A staging map: LDS 16B-chunk c = tid + 256j (linear write, conflict-free);
  // read side expects chunk c to hold source slot s = (c&7)^(row&7), row=c>>3.
  const int arow = tid >> 3;                          // + 32j
  const int acol = ((tid & 7) ^ ((tid >> 3) & 7)) * 8;  // f32 col base
  const int brow = lane >> 3;
  const int bsrc = ((lane & 7) ^ ((lane >> 3) & 7)) * 8;

  f32x4 xa[4][2];
  auto A_ISSUE = [&](int k0) {
#pragma unroll
    for (int j = 0; j < 4; ++j) {
      const float* p = X + (m0 + arow + 32 * j) * (size_t)K + k0 + acol;
      xa[j][0] = *(const f32x4*)p;
      xa[j][1] = *(const f32x4*)(p + 4);
    }
  };
  auto B_ISSUE = [&](int buf, int k0) {
#pragma unroll
    for (int c = 0; c < 4; ++c) {
      const int seg = c * 4 + wave;
      llds16(Bs + buf * 8192 + seg * 512,
             Bw + (n0 + seg * 8 + brow) * (size_t)K + k0 + bsrc);
    }
  };
  auto A_WRITE = [&](int buf) {
#pragma unroll
    for (int j = 0; j < 4; ++j) {
      union { u16 us[8]; uint4 u4; } p;
#pragma unroll
      for (int e = 0; e < 4; ++e) {
        const float v0 = xa[j][0][e], v1 = xa[j][1][e];
        sx[j] += v0 + v1;
        qx[j] += v0 * v0 + v1 * v1;
        p.us[e] = f2bf(v0);
        p.us[4 + e] = f2bf(v1);
      }
      *(uint4*)(As + buf * 8192 + (tid + 256 * j) * 8) = p.u4;
    }
  };

  const int NT = K / 64;   // 32
  // prologue
  A_ISSUE(0);
  B_ISSUE(0, 0);
  asm volatile("s_waitcnt vmcnt(4)" ::: "memory");   // A regs landed (B's 4 younger)
  A_WRITE(0);
  asm volatile("s_waitcnt vmcnt(0)" ::: "memory");   // B in LDS
  asm volatile("s_waitcnt lgkmcnt(0)" ::: "memory");
  __builtin_amdgcn_s_barrier();
  asm volatile("" ::: "memory");

  for (int t = 0; t < NT; ++t) {
    const int cur = t & 1;
    const bool more = (t + 1 < NT);
    if (more) { A_ISSUE((t + 1) * 64); B_ISSUE(cur ^ 1, (t + 1) * 64); }

    const u16* Ab = As + cur * 8192;
    const u16* Bb = Bs + cur * 8192;
#pragma unroll
    for (int ks = 0; ks < 2; ++ks) {
      bf16x8 af[4], bfr[4];
#pragma unroll
      for (int m = 0; m < 4; ++m)
        af[m] = *(const bf16x8*)&Ab[(wr + m * 16 + lrow) * 64 +
                                    ((unsigned)((ks * 4 + lk) ^ (lane & 7))) * 8];
#pragma unroll
      for (int n = 0; n < 4; ++n)
        bfr[n] = *(const bf16x8*)&Bb[(wc + n * 16 + lrow) * 64 +
                                     ((unsigned)((ks * 4 + lk) ^ (lane & 7))) * 8];
      __builtin_amdgcn_s_setprio(1);
#pragma unroll
      for (int m = 0; m < 4; ++m)
#pragma unroll
        for (int n = 0; n < 4; ++n)
          acc[m][n] = __builtin_amdgcn_mfma_f32_16x16x32_bf16(af[m], bfr[n],
                                                              acc[m][n], 0, 0, 0);
      __builtin_amdgcn_s_setprio(0);
    }
    if (more) {
      asm volatile("s_waitcnt vmcnt(4)" ::: "memory");  // next A regs landed
      A_WRITE(cur ^ 1);                                  // write other buffer
      asm volatile("s_waitcnt vmcnt(0)" ::: "memory");  // next B in LDS
    }
    asm volatile("s_waitcnt lgkmcnt(0)" ::: "memory");
    __builtin_amdgcn_s_barrier();
    asm volatile("" ::: "memory");
  }

  // ---- epilogue: finalize stats, apply LN correction, LDS-transpose, store
  float ucol[4], wcol[4];
#pragma unroll
  for (int n = 0; n < 4; ++n) {
    const int c = wc + n * 16 + lrow;
    ucol[n] = uu[n0 + c];
    wcol[n] = wvv[n0 + c];
  }
#pragma unroll
  for (int j = 0; j < 4; ++j) {
#pragma unroll
    for (int off = 1; off < 8; off <<= 1) {
      sx[j] += __shfl_xor(sx[j], off, 64);
      qx[j] += __shfl_xor(qx[j], off, 64);
    }
  }
  if ((lane & 7) == 0) {
#pragma unroll
    for (int j = 0; j < 4; ++j) {
      const int r = (tid >> 3) + 32 * j;
      const float mu = sx[j] * (1.0f / 2048.0f);
      const float var = qx[j] * (1.0f / 2048.0f) - mu * mu;
      stats[r][0] = mu;
      stats[r][1] = rsqrtf(var + LN_EPS);
    }
  }
  asm volatile("s_waitcnt lgkmcnt(0)" ::: "memory");
  __builtin_amdgcn_s_barrier();
  asm volatile("" ::: "memory");

#pragma unroll
  for (int m = 0; m < 4; ++m) {
#pragma unroll
    for (int r = 0; r < 4; ++r) {
      const int row = wr + m * 16 + lk * 4 + r;
      const float mu = stats[row][0], rs = stats[row][1];
#pragma unroll
      for (int n = 0; n < 4; ++n) {
        const int c = wc + n * 16 + lrow;
        const float val = rs * (acc[m][n][r] - mu * ucol[n]) + wcol[n];
        Cs[row * 128 + ((c + ((row >> 2) << 3)) & 127)] = val;
      }
    }
  }
  asm volatile("s_waitcnt lgkmcnt(0)" ::: "memory");
  __builtin_amdgcn_s_barrier();
  asm volatile("" ::: "memory");

#pragma unroll
  for (int j = 0; j < 8; ++j) {
    const int flat = tid * 8 + j * 2048;
    const int row = flat >> 7, c = flat & 127;
    const int cp = (c + ((row >> 2) << 3)) & 127;
    const f32x4 c0 = *(const f32x4*)&Cs[row * 128 + cp];
    const f32x4 c1 = *(const f32x4*)&Cs[row * 128 + cp + 4];
    union { u16 us[8]; uint4 u; } p;
    p.us[0] = f2bf(fmaxf(c0[0], 0.0f)); p.us[1] = f2bf(fmaxf(c0[1], 0.0f));
    p.us[2] = f2bf(fmaxf(c0[2], 0.0f)); p.us[3] = f2bf(fmaxf(c0[3], 0.0f));
    p.us[4] = f2bf(fmaxf(c1[0], 0.0f)); p.us[5] = f2bf(fmaxf(c1[1], 0.0f));
    p.us[6] = f2bf(fmaxf(c1[2], 0.0f)); p.us[7] = f2bf(fmaxf(c1[3], 0.0f));
    *(uint4*)&h2out[(m0 + row) * 512 + n0 + c] = p.u;
  }
}

// ---- gemm2: out = h2*uwb^T + up_b + resid; K=512 fixed, fully unrolled.
// R5 structure + resid loads spread into the K-loop (counted into vmcnt).
__global__ __launch_bounds__(256) void gemm2(
    const u16* __restrict__ A, const u16* __restrict__ Bw,
    int M, const float* __restrict__ bias,
    const float* __restrict__ resid, float* __restrict__ outp) {
  const int K = 512, N = 2048;
  __shared__ __align__(16) char smem[65536];
  u16* As = (u16*)smem;
  u16* Bs = (u16*)(smem + 32768);
  float* Cs = (float*)smem;

  const int tid = threadIdx.x;
  const int wave = tid >> 6, lane = tid & 63;
  const int wr = (wave >> 1) * 64, wc = (wave & 1) * 64;
  const int lrow = lane & 15, lk = lane >> 4;

  const int nwg = gridDim.x;            // 2048, %8==0
  const int wg = (blockIdx.x & 7) * (nwg >> 3) + (blockIdx.x >> 3);
  const int bx = wg & 15, by = wg >> 4; // NX=16
  const size_t m0 = (size_t)by * 128, n0 = (size_t)bx * 128;

  f32x4 acc[4][4] = {};

  const int srow = lane >> 3;
  const int sslot = ((lane & 7) ^ ((lane >> 3) & 7)) * 8;
  auto STAGE = [&](int buf, int k0) {
#pragma unroll
    for (int c = 0; c < 4; ++c) {
      const int seg = c * 4 + wave;
      const int r = seg * 8 + srow;
      llds16(As + buf * 8192 + seg * 512, A + (m0 + r) * (size_t)K + (k0 + sslot));
      llds16(Bs + buf * 8192 + seg * 512, Bw + (n0 + r) * (size_t)K + (k0 + sslot));
    }
  };

  f32x4 rsd[16];
  auto RSD = [&](int j) {
    const int flat = tid * 4 + j * 1024;
    const int row = flat >> 7, c = flat & 127;
    rsd[j] = *(const f32x4*)&resid[(m0 + row) * (size_t)N + n0 + c];
  };

  STAGE(0, 0);                                    // 8 in flight
#pragma unroll
  for (int t = 0; t < 8; ++t) {
    const int cur = t & 1;
    if (t < 7) {
      STAGE(cur ^ 1, (t + 1) * 64);               // +8
      RSD(2 * t); RSD(2 * t + 1);                 // +2
      asm volatile("s_waitcnt vmcnt(10)" ::: "memory");  // tile t landed
    } else {
      RSD(14); RSD(15);
      asm volatile("s_waitcnt vmcnt(4)" ::: "memory");   // STAGE(7) landed
    }
    __builtin_amdgcn_s_barrier();
    asm volatile("" ::: "memory");

    const u16* Ab = As + cur * 8192;
    const u16* Bb = Bs + cur * 8192;
#pragma unroll
    for (int ks = 0; ks < 2; ++ks) {
      bf16x8 af[4], bfr[4];
#pragma unroll
      for (int m = 0; m < 4; ++m)
        af[m] = *(const bf16x8*)&Ab[(wr + m * 16 + lrow) * 64 +
                                    ((unsigned)((ks * 4 + lk) ^ (lane & 7))) * 8];
#pragma unroll
      for (int n = 0; n < 4; ++n)
        bfr[n] = *(const bf16x8*)&Bb[(wc + n * 16 + lrow) * 64 +
                                     ((unsigned)((ks * 4 + lk) ^ (lane & 7))) * 8];
      __builtin_amdgcn_s_setprio(1);
#pragma unroll
      for (int m = 0; m < 4; ++m)
#pragma unroll
        for (int n = 0; n < 4; ++n)
          acc[m][n] = __builtin_amdgcn_mfma_f32_16x16x32_bf16(af[m], bfr[n],
                                                              acc[m][n], 0, 0, 0);
      __builtin_amdgcn_s_setprio(0);
    }
    asm volatile("s_waitcnt lgkmcnt(0)" ::: "memory");
    __builtin_amdgcn_s_barrier();
    asm volatile("" ::: "memory");
  }

  // epilogue: bias into Cs (rotated), transpose-read, add resid, f32 store
#pragma unroll
  for (int n = 0; n < 4; ++n) {
    const int c = wc + n * 16 + lrow;
    const float bv = bias[n0 + c];
#pragma unroll
    for (int m = 0; m < 4; ++m) {
#pragma unroll
      for (int r = 0; r < 4; ++r) {
        const int row = wr + m * 16 + lk * 4 + r;
        Cs[row * 128 + ((c + ((row >> 2) << 3)) & 127)] = acc[m][n][r] + bv;
      }
    }
  }
  asm volatile("s_waitcnt lgkmcnt(0)" ::: "memory");
  __builtin_amdgcn_s_barrier();
  asm volatile("" ::: "memory");

#pragma unroll
  for (int j = 0; j < 16; ++j) {
    const int flat = tid * 4 + j * 1024;
    const int row = flat >> 7, c = flat & 127;
    const f32x4 cc = *(const f32x4*)&Cs[row * 128 + ((c + ((row >> 2) << 3)) & 127)];
    f32x4 o;
    o[0] = cc[0] + rsd[j][0]; o[1] = cc[1] + rsd[j][1];
    o[2] = cc[2] + rsd[j][2]; o[3] = cc[3] + rsd[j][3];
    *(f32x4*)&outp[(m0 + row) * (size_t)N + n0 + c] = o;
  }
}

extern "C" void kernel_launch(void* const* d_in, const int* in_sizes, int n_in,
                              void* d_out, int out_size, void* d_ws, size_t ws_size,
                              hipStream_t stream) {
  const float* x         = (const float*)d_in[0];
  const float* down_w    = (const float*)d_in[1];
  const float* down_b    = (const float*)d_in[2];
  const float* up_w      = (const float*)d_in[3];
  const float* up_b      = (const float*)d_in[4];
  const float* ln_g      = (const float*)d_in[5];
  const float* ln_b      = (const float*)d_in[6];
  const float* down_loga = (const float*)d_in[7];
  const float* up_loga   = (const float*)d_in[8];
  const int*   lang      = (const int*)d_in[9];

  const int D = 2048, BNK = 512;
  const int M = in_sizes[0] / D;  // 16384

  char* ws = (char*)d_ws;
  u16*   h2  = (u16*)ws;                                  // [M][512] bf16
  u16*   dwb = (u16*)(ws + (size_t)M * BNK * 2);          // [512][2048] bf16
  u16*   uwb = dwb + (size_t)BNK * D;                     // [2048][512] bf16
  float* u_  = (float*)(uwb + (size_t)D * BNK);           // [512]
  float* wv_ = u_ + BNK;                                  // [512]

  prep_weights<<<(BNK * D) / 256, 256, 0, stream>>>(down_w, up_w, down_loga,
                                                    up_loga, lang, ln_g, dwb, uwb);
  prep_uv<<<BNK / 4, 256, 0, stream>>>(down_w, down_loga, lang, ln_g, ln_b,
                                       down_b, u_, wv_);
  gemm1_ln<<<(M / 128) * (BNK / 128), 256, 0, stream>>>(x, dwb, M, u_, wv_, h2);
  gemm2<<<(M / 128) * (D / 128), 256, 0, stream>>>(h2, uwb, M, up_b, x,
                                                   (float*)d_out);
}

// Round 9
// 148.945 us; speedup vs baseline: 1.2091x; 1.0787x over previous
//
#include <hip/hip_runtime.h>
#include <cstdint>
#include <cstddef>

typedef unsigned short u16;
typedef __attribute__((ext_vector_type(4))) float f32x4;
typedef __attribute__((ext_vector_type(8))) short bf16x8;

#define LN_EPS 1e-5f

__device__ __forceinline__ u16 f2bf(float f) {
  unsigned int u = __float_as_uint(f);
  u += 0x7FFFu + ((u >> 16) & 1u);
  return (u16)(u >> 16);
}

__device__ __forceinline__ float l0gate(float loga) {
  float s = 1.0f / (1.0f + expf(-loga));
  float v = s * 1.2f - 0.1f;   // sigmoid*(zeta-gamma)+gamma
  return fminf(fmaxf(v, 0.0f), 1.0f);
}

__device__ __forceinline__ void llds16(u16* lds, const u16* g) {
  __builtin_amdgcn_global_load_lds(
      (const __attribute__((address_space(1))) unsigned int*)g,
      (__attribute__((address_space(3))) unsigned int*)lds, 16, 0, 0);
}

// ---- prep: fold L0 gate into bf16 weights ----
__global__ __launch_bounds__(256) void prep_weights(
    const float* __restrict__ dw, const float* __restrict__ uw,
    const float* __restrict__ dloga, const float* __restrict__ uloga,
    const int* __restrict__ lang,
    u16* __restrict__ dwb, u16* __restrict__ uwb) {
  const int lid = lang[0];
  const unsigned i = blockIdx.x * 256u + threadIdx.x;
  dwb[i] = f2bf(dw[i] * l0gate(dloga[lid * 2048 + (i & 2047u)]));
  uwb[i] = f2bf(uw[i] * l0gate(uloga[lid * 512 + (i & 511u)]));
}

// ---- LayerNorm over D=2048 + bf16 cast; one block per token row ----
__global__ __launch_bounds__(256) void ln_kernel(
    const float* __restrict__ x, const float* __restrict__ g,
    const float* __restrict__ b, u16* __restrict__ h1) {
  const int row = blockIdx.x;
  const int tid = threadIdx.x;
  const float4* xr = (const float4*)(x + (size_t)row * 2048);
  float4 v0 = xr[tid * 2 + 0];
  float4 v1 = xr[tid * 2 + 1];
  float s = v0.x + v0.y + v0.z + v0.w + v1.x + v1.y + v1.z + v1.w;
  float q = v0.x * v0.x + v0.y * v0.y + v0.z * v0.z + v0.w * v0.w +
            v1.x * v1.x + v1.y * v1.y + v1.z * v1.z + v1.w * v1.w;
#pragma unroll
  for (int off = 32; off > 0; off >>= 1) {
    s += __shfl_down(s, off, 64);
    q += __shfl_down(q, off, 64);
  }
  __shared__ float ss[4], sq[4], sstat[2];
  const int wave = tid >> 6, lane = tid & 63;
  if (lane == 0) { ss[wave] = s; sq[wave] = q; }
  __syncthreads();
  if (tid == 0) {
    float S = ss[0] + ss[1] + ss[2] + ss[3];
    float Q = sq[0] + sq[1] + sq[2] + sq[3];
    float mu = S * (1.0f / 2048.0f);
    float var = Q * (1.0f / 2048.0f) - mu * mu;
    sstat[0] = mu;
    sstat[1] = rsqrtf(var + LN_EPS);
  }
  __syncthreads();
  const float mu = sstat[0], rs = sstat[1];
  const float4* g4 = (const float4*)g;
  const float4* b4 = (const float4*)b;
  float4 ga = g4[tid * 2], gb = g4[tid * 2 + 1];
  float4 ba = b4[tid * 2], bb = b4[tid * 2 + 1];
  union { u16 us[8]; uint4 u; } p;
  p.us[0] = f2bf((v0.x - mu) * rs * ga.x + ba.x);
  p.us[1] = f2bf((v0.y - mu) * rs * ga.y + ba.y);
  p.us[2] = f2bf((v0.z - mu) * rs * ga.z + ba.z);
  p.us[3] = f2bf((v0.w - mu) * rs * ga.w + ba.w);
  p.us[4] = f2bf((v1.x - mu) * rs * gb.x + bb.x);
  p.us[5] = f2bf((v1.y - mu) * rs * gb.y + bb.y);
  p.us[6] = f2bf((v1.z - mu) * rs * gb.z + bb.z);
  p.us[7] = f2bf((v1.w - mu) * rs * gb.w + bb.w);
  ((uint4*)(h1 + (size_t)row * 2048))[tid] = p.u;
}

// ---- gemm1: h2 = relu(h1 * dwb^T + down_b), bf16 out ----
// 128x128 tile, BK=64, dbuf counted-vmcnt, both-sides T2 swizzle, T1 XCD swizzle.
// (R5's gemm_bt<1> — measured ~28 us, never in top-5.)
__global__ __launch_bounds__(256) void gemm1(
    const u16* __restrict__ A, const u16* __restrict__ Bw,
    int M, int K, int NX,
    const float* __restrict__ bias,
    u16* __restrict__ outp) {
  const int N = 512;
  __shared__ __align__(16) char smem[65536];
  u16* As = (u16*)smem;
  u16* Bs = (u16*)(smem + 32768);
  float* Cs = (float*)smem;

  const int tid = threadIdx.x;
  const int wave = tid >> 6, lane = tid & 63;
  const int wr = (wave >> 1) * 64, wc = (wave & 1) * 64;
  const int lrow = lane & 15, lk = lane >> 4;

  const int nwg = gridDim.x;
  const int wg = (blockIdx.x & 7) * (nwg >> 3) + (blockIdx.x >> 3);
  const int bx = wg % NX, by = wg / NX;
  const size_t m0 = (size_t)by * 128, n0 = (size_t)bx * 128;

  f32x4 acc[4][4] = {};

  const int srow = lane >> 3;
  const int sslot = ((lane & 7) ^ ((lane >> 3) & 7)) * 8;
  auto STAGE = [&](int buf, int k0) {
#pragma unroll
    for (int c = 0; c < 4; ++c) {
      const int seg = c * 4 + wave;
      const int r = seg * 8 + srow;
      llds16(As + buf * 8192 + seg * 512, A + (m0 + r) * (size_t)K + (k0 + sslot));
      llds16(Bs + buf * 8192 + seg * 512, Bw + (n0 + r) * (size_t)K + (k0 + sslot));
    }
  };

  const int NT = K >> 6;
  STAGE(0, 0);

  for (int t = 0; t < NT; ++t) {
    const int cur = t & 1;
    if (t + 1 < NT) {
      STAGE(cur ^ 1, (t + 1) << 6);
      asm volatile("s_waitcnt vmcnt(8)" ::: "memory");
    } else {
      asm volatile("s_waitcnt vmcnt(0)" ::: "memory");
    }
    __builtin_amdgcn_s_barrier();
    asm volatile("" ::: "memory");

    const u16* Ab = As + cur * 8192;
    const u16* Bb = Bs + cur * 8192;
#pragma unroll
    for (int ks = 0; ks < 2; ++ks) {
      bf16x8 af[4], bfr[4];
#pragma unroll
      for (int m = 0; m < 4; ++m)
        af[m] = *(const bf16x8*)&Ab[(wr + m * 16 + lrow) * 64 +
                                    ((unsigned)((ks * 4 + lk) ^ (lane & 7))) * 8];
#pragma unroll
      for (int n = 0; n < 4; ++n)
        bfr[n] = *(const bf16x8*)&Bb[(wc + n * 16 + lrow) * 64 +
                                     ((unsigned)((ks * 4 + lk) ^ (lane & 7))) * 8];
      __builtin_amdgcn_s_setprio(1);
#pragma unroll
      for (int m = 0; m < 4; ++m)
#pragma unroll
        for (int n = 0; n < 4; ++n)
          acc[m][n] = __builtin_amdgcn_mfma_f32_16x16x32_bf16(af[m], bfr[n],
                                                              acc[m][n], 0, 0, 0);
      __builtin_amdgcn_s_setprio(0);
    }
    asm volatile("s_waitcnt lgkmcnt(0)" ::: "memory");
    __builtin_amdgcn_s_barrier();
    asm volatile("" ::: "memory");
  }

  // epilogue: +bias, relu, LDS-transpose, coalesced bf16 store
#pragma unroll
  for (int n = 0; n < 4; ++n) {
    const int c = wc + n * 16 + lrow;
    const float bv = bias[n0 + c];
#pragma unroll
    for (int m = 0; m < 4; ++m) {
#pragma unroll
      for (int r = 0; r < 4; ++r) {
        const int row = wr + m * 16 + lk * 4 + r;
        Cs[row * 128 + ((c + ((row >> 2) << 3)) & 127)] = acc[m][n][r] + bv;
      }
    }
  }
  asm volatile("s_waitcnt lgkmcnt(0)" ::: "memory");
  __builtin_amdgcn_s_barrier();
  asm volatile("" ::: "memory");

#pragma unroll
  for (int j = 0; j < 8; ++j) {
    const int flat = tid * 8 + j * 2048;
    const int row = flat >> 7, c = flat & 127;
    const int cp = (c + ((row >> 2) << 3)) & 127;
    const f32x4 c0 = *(const f32x4*)&Cs[row * 128 + cp];
    const f32x4 c1 = *(const f32x4*)&Cs[row * 128 + cp + 4];
    union { u16 us[8]; uint4 u; } p;
    p.us[0] = f2bf(fmaxf(c0[0], 0.0f)); p.us[1] = f2bf(fmaxf(c0[1], 0.0f));
    p.us[2] = f2bf(fmaxf(c0[2], 0.0f)); p.us[3] = f2bf(fmaxf(c0[3], 0.0f));
    p.us[4] = f2bf(fmaxf(c1[0], 0.0f)); p.us[5] = f2bf(fmaxf(c1[1], 0.0f));
    p.us[6] = f2bf(fmaxf(c1[2], 0.0f)); p.us[7] = f2bf(fmaxf(c1[3], 0.0f));
    *(uint4*)&outp[(m0 + row) * (size_t)N + n0 + c] = p.u;
  }
}

// ---- gemm2: out = h2*uwb^T + up_b + resid; K=512 fixed, fully unrolled.
// Resid loads spread into the K-loop (counted into vmcnt). (R8 version, ~45 us.)
__global__ __launch_bounds__(256) void gemm2(
    const u16* __restrict__ A, const u16* __restrict__ Bw,
    int M, const float* __restrict__ bias,
    const float* __restrict__ resid, float* __restrict__ outp) {
  const int K = 512, N = 2048;
  __shared__ __align__(16) char smem[65536];
  u16* As = (u16*)smem;
  u16* Bs = (u16*)(smem + 32768);
  float* Cs = (float*)smem;

  const int tid = threadIdx.x;
  const int wave = tid >> 6, lane = tid & 63;
  const int wr = (wave >> 1) * 64, wc = (wave & 1) * 64;
  const int lrow = lane & 15, lk = lane >> 4;

  const int nwg = gridDim.x;            // 2048, %8==0
  const int wg = (blockIdx.x & 7) * (nwg >> 3) + (blockIdx.x >> 3);
  const int bx = wg & 15, by = wg >> 4; // NX=16
  const size_t m0 = (size_t)by * 128, n0 = (size_t)bx * 128;

  f32x4 acc[4][4] = {};

  const int srow = lane >> 3;
  const int sslot = ((lane & 7) ^ ((lane >> 3) & 7)) * 8;
  auto STAGE = [&](int buf, int k0) {
#pragma unroll
    for (int c = 0; c < 4; ++c) {
      const int seg = c * 4 + wave;
      const int r = seg * 8 + srow;
      llds16(As + buf * 8192 + seg * 512, A + (m0 + r) * (size_t)K + (k0 + sslot));
      llds16(Bs + buf * 8192 + seg * 512, Bw + (n0 + r) * (size_t)K + (k0 + sslot));
    }
  };

  f32x4 rsd[16];
  auto RSD = [&](int j) {
    const int flat = tid * 4 + j * 1024;
    const int row = flat >> 7, c = flat & 127;
    rsd[j] = *(const f32x4*)&resid[(m0 + row) * (size_t)N + n0 + c];
  };

  STAGE(0, 0);                                    // 8 in flight
#pragma unroll
  for (int t = 0; t < 8; ++t) {
    const int cur = t & 1;
    if (t < 7) {
      STAGE(cur ^ 1, (t + 1) * 64);               // +8
      RSD(2 * t); RSD(2 * t + 1);                 // +2
      asm volatile("s_waitcnt vmcnt(10)" ::: "memory");  // tile t landed
    } else {
      RSD(14); RSD(15);
      asm volatile("s_waitcnt vmcnt(4)" ::: "memory");   // STAGE(7) landed
    }
    __builtin_amdgcn_s_barrier();
    asm volatile("" ::: "memory");

    const u16* Ab = As + cur * 8192;
    const u16* Bb = Bs + cur * 8192;
#pragma unroll
    for (int ks = 0; ks < 2; ++ks) {
      bf16x8 af[4], bfr[4];
#pragma unroll
      for (int m = 0; m < 4; ++m)
        af[m] = *(const bf16x8*)&Ab[(wr + m * 16 + lrow) * 64 +
                                    ((unsigned)((ks * 4 + lk) ^ (lane & 7))) * 8];
#pragma unroll
      for (int n = 0; n < 4; ++n)
        bfr[n] = *(const bf16x8*)&Bb[(wc + n * 16 + lrow) * 64 +
                                     ((unsigned)((ks * 4 + lk) ^ (lane & 7))) * 8];
      __builtin_amdgcn_s_setprio(1);
#pragma unroll
      for (int m = 0; m < 4; ++m)
#pragma unroll
        for (int n = 0; n < 4; ++n)
          acc[m][n] = __builtin_amdgcn_mfma_f32_16x16x32_bf16(af[m], bfr[n],
                                                              acc[m][n], 0, 0, 0);
      __builtin_amdgcn_s_setprio(0);
    }
    asm volatile("s_waitcnt lgkmcnt(0)" ::: "memory");
    __builtin_amdgcn_s_barrier();
    asm volatile("" ::: "memory");
  }

  // epilogue: bias into Cs (rotated), transpose-read, add resid, f32 store
#pragma unroll
  for (int n = 0; n < 4; ++n) {
    const int c = wc + n * 16 + lrow;
    const float bv = bias[n0 + c];
#pragma unroll
    for (int m = 0; m < 4; ++m) {
#pragma unroll
      for (int r = 0; r < 4; ++r) {
        const int row = wr + m * 16 + lk * 4 + r;
        Cs[row * 128 + ((c + ((row >> 2) << 3)) & 127)] = acc[m][n][r] + bv;
      }
    }
  }
  asm volatile("s_waitcnt lgkmcnt(0)" ::: "memory");
  __builtin_amdgcn_s_barrier();
  asm volatile("" ::: "memory");

#pragma unroll
  for (int j = 0; j < 16; ++j) {
    const int flat = tid * 4 + j * 1024;
    const int row = flat >> 7, c = flat & 127;
    const f32x4 cc = *(const f32x4*)&Cs[row * 128 + ((c + ((row >> 2) << 3)) & 127)];
    f32x4 o;
    o[0] = cc[0] + rsd[j][0]; o[1] = cc[1] + rsd[j][1];
    o[2] = cc[2] + rsd[j][2]; o[3] = cc[3] + rsd[j][3];
    *(f32x4*)&outp[(m0 + row) * (size_t)N + n0 + c] = o;
  }
}

extern "C" void kernel_launch(void* const* d_in, const int* in_sizes, int n_in,
                              void* d_out, int out_size, void* d_ws, size_t ws_size,
                              hipStream_t stream) {
  const float* x         = (const float*)d_in[0];
  const float* down_w    = (const float*)d_in[1];
  const float* down_b    = (const float*)d_in[2];
  const float* up_w      = (const float*)d_in[3];
  const float* up_b      = (const float*)d_in[4];
  const float* ln_g      = (const float*)d_in[5];
  const float* ln_b      = (const float*)d_in[6];
  const float* down_loga = (const float*)d_in[7];
  const float* up_loga   = (const float*)d_in[8];
  const int*   lang      = (const int*)d_in[9];

  const int D = 2048, BNK = 512;
  const int M = in_sizes[0] / D;  // 16384

  char* ws = (char*)d_ws;
  u16* h1  = (u16*)ws;                                   // [M][D] bf16
  u16* h2  = (u16*)(ws + (size_t)M * D * 2);             // [M][BNK] bf16
  u16* dwb = (u16*)(ws + (size_t)M * D * 2 + (size_t)M * BNK * 2);  // [BNK][D]
  u16* uwb = dwb + (size_t)BNK * D;                      // [D][BNK]

  prep_weights<<<(BNK * D) / 256, 256, 0, stream>>>(down_w, up_w, down_loga,
                                                    up_loga, lang, dwb, uwb);
  ln_kernel<<<M, 256, 0, stream>>>(x, ln_g, ln_b, h1);
  gemm1<<<(M / 128) * (BNK / 128), 256, 0, stream>>>(h1, dwb, M, D, BNK / 128,
                                                     down_b, h2);
  gemm2<<<(M / 128) * (D / 128), 256, 0, stream>>>(h2, uwb, M, up_b, x,
                                                   (float*)d_out);
}